// Round 1
// baseline (218.434 us; speedup 1.0000x reference)
//
#include <hip/hip_runtime.h>
#include <hip/hip_bf16.h>

// Problem constants: B=8, H=W=32 (seq=1024), C=512, heads=8, head_dim=64, groups=32 (16 ch/group)
#define SEQ   1024
#define CH    512
#define NHEAD 8
#define HDIM  64
#define NGRP  32
#define BATCH 8
#define MTOT  (BATCH * SEQ)   // 8192

using short8  = __attribute__((ext_vector_type(8))) short;
using floatx4 = __attribute__((ext_vector_type(4))) float;

__device__ inline unsigned short f2bf(float f) {
  __hip_bfloat16 h = __float2bfloat16(f);
  return __builtin_bit_cast(unsigned short, h);
}

// ---------------------------------------------------------------------------
// K1: convert + transpose weights to bf16  (wqkv_t: 1536x512, wout_t: 512x512)
// ---------------------------------------------------------------------------
__global__ __launch_bounds__(256) void convert_w_kernel(
    const float* __restrict__ wqkv, const float* __restrict__ wout,
    unsigned short* __restrict__ wqkvt, unsigned short* __restrict__ woutt) {
  int tid = blockIdx.x * 256 + threadIdx.x;
  const int NQ = 1536 * 512;
  if (tid < NQ) {
    int n = tid >> 9, k = tid & 511;
    wqkvt[tid] = f2bf(wqkv[k * 1536 + n]);
  } else {
    int t = tid - NQ;                 // < 512*512
    int n = t >> 9, k = t & 511;
    woutt[t] = f2bf(wout[k * 512 + n]);
  }
}

// ---------------------------------------------------------------------------
// K2: GroupNorm.  One block per (batch, group). Normalize over 1024 rows x 16 ch.
// ---------------------------------------------------------------------------
__global__ __launch_bounds__(256) void groupnorm_kernel(
    const float* __restrict__ x, const float* __restrict__ gsc,
    const float* __restrict__ gbs, unsigned short* __restrict__ xn) {
  int bg = blockIdx.x;
  int b = bg >> 5, g = bg & 31;
  const size_t base = (size_t)b * SEQ * CH + g * 16;
  int tid = threadIdx.x;

  float s = 0.f, sq = 0.f;
  for (int i = tid; i < 4096; i += 256) {          // 1024 rows * 4 float4
    int r = i >> 2, c4 = (i & 3) * 4;
    float4 v = *(const float4*)(x + base + (size_t)r * CH + c4);
    s  += v.x + v.y + v.z + v.w;
    sq += v.x * v.x + v.y * v.y + v.z * v.z + v.w * v.w;
  }
  for (int off = 1; off < 64; off <<= 1) {
    s  += __shfl_xor(s, off);
    sq += __shfl_xor(sq, off);
  }
  __shared__ float ls[4], lq[4];
  int wid = tid >> 6, lane = tid & 63;
  if (lane == 0) { ls[wid] = s; lq[wid] = sq; }
  __syncthreads();
  float ts = ls[0] + ls[1] + ls[2] + ls[3];
  float tq = lq[0] + lq[1] + lq[2] + lq[3];
  const float inv_n = 1.0f / 16384.0f;
  float mean = ts * inv_n;
  float var  = tq * inv_n - mean * mean;
  float rstd = rsqrtf(var + 1e-6f);

  for (int i = tid; i < 4096; i += 256) {
    int r = i >> 2, c4 = (i & 3) * 4;
    float4 v = *(const float4*)(x + base + (size_t)r * CH + c4);
    int cb = g * 16 + c4;
    ushort4 o;
    o.x = f2bf((v.x - mean) * rstd * gsc[cb + 0] + gbs[cb + 0]);
    o.y = f2bf((v.y - mean) * rstd * gsc[cb + 1] + gbs[cb + 1]);
    o.z = f2bf((v.z - mean) * rstd * gsc[cb + 2] + gbs[cb + 2]);
    o.w = f2bf((v.w - mean) * rstd * gsc[cb + 3] + gbs[cb + 3]);
    *(ushort4*)(xn + (size_t)(b * SEQ + r) * CH + g * 16 + c4) = o;
  }
}

// ---------------------------------------------------------------------------
// K3/K5: GEMM  C = A(MxK) * Bt(NxK)^T, bf16 in, fp32 accumulate.
// 128x128 block tile, 4 waves each 64x64 (4x4 of 16x16x32 MFMA), BK=64.
// EPI 0: +bias, scatter into q(h,s,d), k(h,s,d), vt(h,d,s) bf16
// EPI 1: +bias +residual(fp32), write fp32 out
// ---------------------------------------------------------------------------
template <int EPI>
__global__ __launch_bounds__(256) void gemm_bt_kernel(
    const unsigned short* __restrict__ A, const unsigned short* __restrict__ Bt,
    int M, int N, int K,
    const float* __restrict__ bias, const float* __restrict__ resid,
    float* __restrict__ outf,
    unsigned short* __restrict__ qb, unsigned short* __restrict__ kb,
    unsigned short* __restrict__ vtb) {
  __shared__ unsigned short LA[128 * 72];   // stride 72 (pad 8) -> 2-way-free banks
  __shared__ unsigned short LB[128 * 72];

  const int tid = threadIdx.x;
  const int wid = tid >> 6, lane = tid & 63;
  const int quad = lane >> 4, m16 = lane & 15;
  const int wm = (wid & 1) * 64, wn = (wid >> 1) * 64;
  const int m0 = blockIdx.y * 128, n0 = blockIdx.x * 128;

  floatx4 acc[4][4];
  for (int i = 0; i < 4; ++i)
    for (int j = 0; j < 4; ++j) acc[i][j] = 0.f;

  for (int k0 = 0; k0 < K; k0 += 64) {
    for (int i = 0; i < 4; ++i) {
      int c = tid + i * 256;            // 1024 chunks of 16B
      int r = c >> 3, c8 = (c & 7) * 8;
      *(int4*)&LA[r * 72 + c8] = *(const int4*)(A  + (size_t)(m0 + r) * K + k0 + c8);
      *(int4*)&LB[r * 72 + c8] = *(const int4*)(Bt + (size_t)(n0 + r) * K + k0 + c8);
    }
    __syncthreads();
    for (int kq = 0; kq < 2; ++kq) {
      short8 af[4], bf[4];
      for (int mi = 0; mi < 4; ++mi)
        af[mi] = *(const short8*)&LA[(wm + mi * 16 + m16) * 72 + kq * 32 + quad * 8];
      for (int ni = 0; ni < 4; ++ni)
        bf[ni] = *(const short8*)&LB[(wn + ni * 16 + m16) * 72 + kq * 32 + quad * 8];
      for (int mi = 0; mi < 4; ++mi)
        for (int ni = 0; ni < 4; ++ni)
          acc[mi][ni] = __builtin_amdgcn_mfma_f32_16x16x32_bf16(af[mi], bf[ni], acc[mi][ni], 0, 0, 0);
    }
    __syncthreads();
  }

  // Epilogue.  C/D layout: row = quad*4+reg, col = lane&15  (HW-verified)
  for (int mi = 0; mi < 4; ++mi) {
    for (int ni = 0; ni < 4; ++ni) {
      int gn = n0 + wn + ni * 16 + m16;
      for (int reg = 0; reg < 4; ++reg) {
        int gm = m0 + wm + mi * 16 + quad * 4 + reg;
        float v = acc[mi][ni][reg] + bias[gn];
        if (EPI == 0) {
          int part = gn >> 9;           // 0=q 1=k 2=v
          int rem = gn & 511;
          int h = rem >> 6, d = rem & 63;
          int b = gm >> 10, sp = gm & 1023;
          int head = b * NHEAD + h;
          unsigned short bv = f2bf(v);
          if (part == 0)      qb[((size_t)head * SEQ + sp) * HDIM + d] = bv;
          else if (part == 1) kb[((size_t)head * SEQ + sp) * HDIM + d] = bv;
          else                vtb[((size_t)head * HDIM + d) * SEQ + sp] = bv;
        } else {
          outf[(size_t)gm * N + gn] = v + resid[(size_t)gm * N + gn];
        }
      }
    }
  }
}

// ---------------------------------------------------------------------------
// K4: flash attention.  Block = (q-tile of 128 rows) x (head).  4 waves,
// each wave owns 32 Q rows.  Online softmax; P round-trips LDS (C->A layout).
// ---------------------------------------------------------------------------
__global__ __launch_bounds__(256) void attn_kernel(
    const unsigned short* __restrict__ qbuf, const unsigned short* __restrict__ kbuf,
    const unsigned short* __restrict__ vtbuf, unsigned short* __restrict__ ao) {
  const int qt = blockIdx.x, head = blockIdx.y;
  const int b = head >> 3, h = head & 7;
  const int tid = threadIdx.x, wid = tid >> 6, lane = tid & 63;
  const int quad = lane >> 4, m16 = lane & 15;

  __shared__ unsigned short sA[128 * 136];  // K-tile (stride 72) then P-tile (stride 136)
  __shared__ unsigned short sB[64 * 136];   // Vt-tile (stride 136)

  // Q fragments in registers (A-operand layout: A[m=lane&15][k=quad*8+j])
  short8 aq[2][2];
  for (int mi = 0; mi < 2; ++mi)
    for (int kq = 0; kq < 2; ++kq)
      aq[mi][kq] = *(const short8*)(qbuf +
          ((size_t)head * SEQ + qt * 128 + wid * 32 + mi * 16 + m16) * HDIM + kq * 32 + quad * 8);

  float mrun[2][4], lrun[2][4];
  floatx4 o[2][4];
  for (int mi = 0; mi < 2; ++mi)
    for (int r = 0; r < 4; ++r) { mrun[mi][r] = -1e30f; lrun[mi][r] = 0.f; }
  for (int mi = 0; mi < 2; ++mi)
    for (int ni = 0; ni < 4; ++ni) o[mi][ni] = 0.f;

  for (int kt = 0; kt < 8; ++kt) {
    // stage K tile (128x64) and Vt tile (64x128)
    for (int i = 0; i < 4; ++i) {
      int c = tid + i * 256;
      int r = c >> 3, c8 = (c & 7) * 8;
      *(int4*)&sA[r * 72 + c8] =
          *(const int4*)(kbuf + ((size_t)head * SEQ + kt * 128 + r) * HDIM + c8);
      int d = c >> 4, c16 = (c & 15) * 8;
      *(int4*)&sB[d * 136 + c16] =
          *(const int4*)(vtbuf + ((size_t)head * HDIM + d) * SEQ + kt * 128 + c16);
    }
    __syncthreads();

    // S = Q K^T  (2 m-frags x 8 n-frags)
    floatx4 s[2][8];
    for (int mi = 0; mi < 2; ++mi)
      for (int nj = 0; nj < 8; ++nj) s[mi][nj] = 0.f;
    for (int nj = 0; nj < 8; ++nj) {
      short8 bk0 = *(const short8*)&sA[(nj * 16 + m16) * 72 + quad * 8];
      short8 bk1 = *(const short8*)&sA[(nj * 16 + m16) * 72 + 32 + quad * 8];
      for (int mi = 0; mi < 2; ++mi) {
        s[mi][nj] = __builtin_amdgcn_mfma_f32_16x16x32_bf16(aq[mi][0], bk0, s[mi][nj], 0, 0, 0);
        s[mi][nj] = __builtin_amdgcn_mfma_f32_16x16x32_bf16(aq[mi][1], bk1, s[mi][nj], 0, 0, 0);
      }
    }

    // online softmax per row (row = quad*4+reg; 16 lanes of a quad share a row)
    for (int mi = 0; mi < 2; ++mi) {
      for (int reg = 0; reg < 4; ++reg) {
        float mx = -1e30f;
        for (int nj = 0; nj < 8; ++nj) {
          float v = s[mi][nj][reg] * 0.015625f;   // (1/8)*(1/8) q,k scaling
          s[mi][nj][reg] = v;
          mx = fmaxf(mx, v);
        }
        for (int off = 1; off < 16; off <<= 1) mx = fmaxf(mx, __shfl_xor(mx, off));
        float mold = mrun[mi][reg];
        float mnew = fmaxf(mold, mx);
        float alpha = __expf(mold - mnew);
        float rs = 0.f;
        for (int nj = 0; nj < 8; ++nj) {
          float p = __expf(s[mi][nj][reg] - mnew);
          s[mi][nj][reg] = p;
          rs += p;
        }
        for (int off = 1; off < 16; off <<= 1) rs += __shfl_xor(rs, off);
        mrun[mi][reg] = mnew;
        lrun[mi][reg] = alpha * lrun[mi][reg] + rs;
        for (int ni = 0; ni < 4; ++ni) o[mi][ni][reg] *= alpha;
      }
    }
    __syncthreads();   // all waves done reading K tile before overwriting with P

    // P: C-layout -> LDS -> A-layout
    for (int mi = 0; mi < 2; ++mi)
      for (int nj = 0; nj < 8; ++nj)
        for (int reg = 0; reg < 4; ++reg)
          sA[(wid * 32 + mi * 16 + quad * 4 + reg) * 136 + nj * 16 + m16] =
              f2bf(s[mi][nj][reg]);
    __syncthreads();

    // O += P V   (A = P 128x128, B = V via Vt rows)
    for (int kk = 0; kk < 4; ++kk) {
      short8 ap0 = *(const short8*)&sA[(wid * 32 + m16) * 136 + kk * 32 + quad * 8];
      short8 ap1 = *(const short8*)&sA[(wid * 32 + 16 + m16) * 136 + kk * 32 + quad * 8];
      for (int ni = 0; ni < 4; ++ni) {
        short8 bv = *(const short8*)&sB[(ni * 16 + m16) * 136 + kk * 32 + quad * 8];
        o[0][ni] = __builtin_amdgcn_mfma_f32_16x16x32_bf16(ap0, bv, o[0][ni], 0, 0, 0);
        o[1][ni] = __builtin_amdgcn_mfma_f32_16x16x32_bf16(ap1, bv, o[1][ni], 0, 0, 0);
      }
    }
    __syncthreads();   // before next stage overwrites sA/sB
  }

  // normalize and write (B, seq, C) bf16
  for (int mi = 0; mi < 2; ++mi) {
    for (int reg = 0; reg < 4; ++reg) {
      float inv = 1.0f / lrun[mi][reg];
      int row = qt * 128 + wid * 32 + mi * 16 + quad * 4 + reg;
      for (int ni = 0; ni < 4; ++ni) {
        int col = h * HDIM + ni * 16 + m16;
        ao[((size_t)(b * SEQ + row)) * CH + col] = f2bf(o[mi][ni][reg] * inv);
      }
    }
  }
}

// ---------------------------------------------------------------------------
extern "C" void kernel_launch(void* const* d_in, const int* in_sizes, int n_in,
                              void* d_out, int out_size, void* d_ws, size_t ws_size,
                              hipStream_t stream) {
  const float* x    = (const float*)d_in[0];
  const float* gsc  = (const float*)d_in[1];
  const float* gbs  = (const float*)d_in[2];
  const float* wqkv = (const float*)d_in[3];
  const float* bqkv = (const float*)d_in[4];
  const float* wout = (const float*)d_in[5];
  const float* bout = (const float*)d_in[6];
  float* out = (float*)d_out;

  char* ws = (char*)d_ws;
  unsigned short* xn    = (unsigned short*)(ws);                 //  8 MB  (8192x512)
  unsigned short* wqkvt = (unsigned short*)(ws + 8388608);       //  1.5 MB (1536x512)
  unsigned short* woutt = (unsigned short*)(ws + 9961472);       //  0.5 MB (512x512)
  unsigned short* qb    = (unsigned short*)(ws + 10485760);      //  8 MB  (64,1024,64)
  unsigned short* kb    = (unsigned short*)(ws + 18874368);      //  8 MB  (64,1024,64)
  unsigned short* vtb   = (unsigned short*)(ws + 27262976);      //  8 MB  (64,64,1024)
  unsigned short* ao    = (unsigned short*)(ws + 35651584);      //  8 MB  (8192x512)

  convert_w_kernel<<<4096, 256, 0, stream>>>(wqkv, wout, wqkvt, woutt);
  groupnorm_kernel<<<256, 256, 0, stream>>>(x, gsc, gbs, xn);
  gemm_bt_kernel<0><<<dim3(12, 64), 256, 0, stream>>>(
      xn, wqkvt, MTOT, 1536, 512, bqkv, nullptr, nullptr, qb, kb, vtb);
  attn_kernel<<<dim3(8, 64), 256, 0, stream>>>(qb, kb, vtb, ao);
  gemm_bt_kernel<1><<<dim3(4, 64), 256, 0, stream>>>(
      ao, woutt, MTOT, 512, 512, bout, x, out, nullptr, nullptr, nullptr);
}

// Round 2
// 173.017 us; speedup vs baseline: 1.2625x; 1.2625x over previous
//
#include <hip/hip_runtime.h>
#include <hip/hip_bf16.h>

// B=8, H=W=32 (seq=1024), C=512, heads=8, head_dim=64, groups=32
#define SEQ   1024
#define CH    512
#define NHEAD 8
#define HDIM  64
#define BATCH 8
#define MTOT  (BATCH * SEQ)   // 8192

using short8  = __attribute__((ext_vector_type(8))) short;
using short4v = __attribute__((ext_vector_type(4))) short;
using floatx4 = __attribute__((ext_vector_type(4))) float;

__device__ inline unsigned short f2bf(float f) {
  __hip_bfloat16 h = __float2bfloat16(f);
  return __builtin_bit_cast(unsigned short, h);
}

// async 16B global->LDS DMA (lane-linear LDS dest required)
__device__ inline void load_lds16(const void* g, void* l) {
  __builtin_amdgcn_global_load_lds(
      (const __attribute__((address_space(1))) unsigned int*)g,
      (__attribute__((address_space(3))) unsigned int*)l, 16, 0, 0);
}

// ---------------------------------------------------------------------------
// K1: coalesced transpose fp32 (RxC) -> bf16 (CxR) via LDS 32x32 tile
// ---------------------------------------------------------------------------
__global__ __launch_bounds__(256) void transpose_bf16_kernel(
    const float* __restrict__ src, unsigned short* __restrict__ dst,
    int R, int C) {
  __shared__ float T[32][33];
  int bx = blockIdx.x * 32, by = blockIdx.y * 32;
  int tx = threadIdx.x & 31, ty = threadIdx.x >> 5;   // ty 0..7
  for (int j = 0; j < 4; ++j)
    T[ty + j * 8][tx] = src[(size_t)(by + ty + j * 8) * C + bx + tx];
  __syncthreads();
  for (int j = 0; j < 4; ++j)
    dst[(size_t)(bx + ty + j * 8) * R + by + tx] = f2bf(T[tx][ty + j * 8]);
}

// ---------------------------------------------------------------------------
// K2: GroupNorm. One block per (batch, group): 1024 rows x 16 ch.
// ---------------------------------------------------------------------------
__global__ __launch_bounds__(256) void groupnorm_kernel(
    const float* __restrict__ x, const float* __restrict__ gsc,
    const float* __restrict__ gbs, unsigned short* __restrict__ xn) {
  int bg = blockIdx.x;
  int b = bg >> 5, g = bg & 31;
  const size_t base = (size_t)b * SEQ * CH + g * 16;
  int tid = threadIdx.x;

  float s = 0.f, sq = 0.f;
  for (int i = tid; i < 4096; i += 256) {
    int r = i >> 2, c4 = (i & 3) * 4;
    float4 v = *(const float4*)(x + base + (size_t)r * CH + c4);
    s  += v.x + v.y + v.z + v.w;
    sq += v.x * v.x + v.y * v.y + v.z * v.z + v.w * v.w;
  }
  for (int off = 1; off < 64; off <<= 1) {
    s  += __shfl_xor(s, off);
    sq += __shfl_xor(sq, off);
  }
  __shared__ float ls[4], lq[4];
  int wid = tid >> 6, lane = tid & 63;
  if (lane == 0) { ls[wid] = s; lq[wid] = sq; }
  __syncthreads();
  float ts = ls[0] + ls[1] + ls[2] + ls[3];
  float tq = lq[0] + lq[1] + lq[2] + lq[3];
  const float inv_n = 1.0f / 16384.0f;
  float mean = ts * inv_n;
  float var  = tq * inv_n - mean * mean;
  float rstd = rsqrtf(var + 1e-6f);

  for (int i = tid; i < 4096; i += 256) {
    int r = i >> 2, c4 = (i & 3) * 4;
    float4 v = *(const float4*)(x + base + (size_t)r * CH + c4);
    int cb = g * 16 + c4;
    ushort4 o;
    o.x = f2bf((v.x - mean) * rstd * gsc[cb + 0] + gbs[cb + 0]);
    o.y = f2bf((v.y - mean) * rstd * gsc[cb + 1] + gbs[cb + 1]);
    o.z = f2bf((v.z - mean) * rstd * gsc[cb + 2] + gbs[cb + 2]);
    o.w = f2bf((v.w - mean) * rstd * gsc[cb + 3] + gbs[cb + 3]);
    *(ushort4*)(xn + (size_t)(b * SEQ + r) * CH + g * 16 + c4) = o;
  }
}

// ---------------------------------------------------------------------------
// K3/K5: GEMM C = A(MxK) * Bt(NxK)^T, bf16 in, fp32 acc.
// 128x128 tile, BK=64, global_load_lds staging with XOR-swizzled LDS.
// EPI 0 (QKV): +bias; q scaled 1/64; q/k direct (h,s,d); v transposed in LDS
//              then coalesced 16B stores to vt (h,d,s).
// EPI 1 (out): +bias +residual, fp32 out.
// ---------------------------------------------------------------------------
template <int EPI>
__global__ __launch_bounds__(256) void gemm_bt_kernel(
    const unsigned short* __restrict__ A, const unsigned short* __restrict__ Bt,
    int K, int N,
    const float* __restrict__ bias, const float* __restrict__ resid,
    float* __restrict__ outf,
    unsigned short* __restrict__ qb, unsigned short* __restrict__ kb,
    unsigned short* __restrict__ vtb) {
  __shared__ alignas(16) unsigned short SM[17408];   // 34.8KB (LA|LB, reused as T)
  unsigned short* LA = SM;           // 128x64 shorts, row stride 64, swizzled
  unsigned short* LB = SM + 8192;

  const int tid = threadIdx.x;
  const int wid = tid >> 6, lane = tid & 63;
  const int quad = lane >> 4, m16 = lane & 15;
  const int sw = m16 & 7;
  const int wm = (wid & 1) * 64, wn = (wid >> 1) * 64;
  const int m0 = blockIdx.y * 128, n0 = blockIdx.x * 128;

  floatx4 acc[4][4];
  for (int i = 0; i < 4; ++i)
    for (int j = 0; j < 4; ++j) acc[i][j] = 0.f;

  for (int k0 = 0; k0 < K; k0 += 64) {
    for (int i = 0; i < 4; ++i) {
      int c = i * 256 + tid;
      int r = c >> 3, kc = c & 7;
      int ksw = (kc ^ (r & 7)) << 3;
      load_lds16(A  + (size_t)(m0 + r) * K + k0 + ksw, &LA[c << 3]);
      load_lds16(Bt + (size_t)(n0 + r) * K + k0 + ksw, &LB[c << 3]);
    }
    __syncthreads();
    for (int kq = 0; kq < 2; ++kq) {
      int csw = (((kq << 2) + quad) ^ sw) << 3;
      short8 af[4], bf[4];
      for (int mi = 0; mi < 4; ++mi)
        af[mi] = *(const short8*)&LA[(wm + mi * 16 + m16) * 64 + csw];
      for (int ni = 0; ni < 4; ++ni)
        bf[ni] = *(const short8*)&LB[(wn + ni * 16 + m16) * 64 + csw];
      for (int mi = 0; mi < 4; ++mi)
        for (int ni = 0; ni < 4; ++ni)
          acc[mi][ni] = __builtin_amdgcn_mfma_f32_16x16x32_bf16(af[mi], bf[ni], acc[mi][ni], 0, 0, 0);
    }
    __syncthreads();
  }

  // C/D layout: row = quad*4+reg, col = lane&15
  if (EPI == 1) {
    for (int mi = 0; mi < 4; ++mi)
      for (int ni = 0; ni < 4; ++ni) {
        int gn = n0 + wn + ni * 16 + m16;
        for (int reg = 0; reg < 4; ++reg) {
          int gm = m0 + wm + mi * 16 + quad * 4 + reg;
          size_t idx = (size_t)gm * N + gn;
          outf[idx] = acc[mi][ni][reg] + bias[gn] + resid[idx];
        }
      }
  } else {
    const int part = blockIdx.x >> 2;        // 0=q 1=k 2=v (block-uniform)
    const int b = m0 >> 10;
    if (part < 2) {
      const float qscale = (part == 0) ? 0.015625f : 1.0f;  // fold (1/8)^2
      unsigned short* dst = (part == 0) ? qb : kb;
      for (int mi = 0; mi < 4; ++mi)
        for (int ni = 0; ni < 4; ++ni) {
          int gn = n0 + wn + ni * 16 + m16;
          int col = gn & 511, h = col >> 6, d = col & 63;
          for (int reg = 0; reg < 4; ++reg) {
            int gm = m0 + wm + mi * 16 + quad * 4 + reg;
            int sp = gm & 1023;
            float v = (acc[mi][ni][reg] + bias[gn]) * qscale;
            dst[((size_t)(b * NHEAD + h) * SEQ + sp) * HDIM + d] = f2bf(v);
          }
        }
    } else {
      // transpose 128x128 tile in LDS: T[local_d][local_sp], stride 136
      __syncthreads();
      for (int mi = 0; mi < 4; ++mi)
        for (int ni = 0; ni < 4; ++ni) {
          int ln = wn + ni * 16 + m16;
          int gn = n0 + ln;
          float bb = bias[gn];
          for (int reg = 0; reg < 4; ++reg) {
            int lm = wm + mi * 16 + quad * 4 + reg;
            SM[ln * 136 + lm] = f2bf(acc[mi][ni][reg] + bb);
          }
        }
      __syncthreads();
      int hbase = ((n0 - 1024) >> 6);          // 2 heads per 128-col block
      for (int j = 0; j < 8; ++j) {
        int c = tid + j * 256;                 // 2048 16B chunks
        int ld = c >> 4, sp8 = (c & 15) * 8;
        int h = hbase + (ld >> 6), d = ld & 63;
        int4 val = *(const int4*)&SM[ld * 136 + sp8];
        *(int4*)(vtb + ((size_t)(b * NHEAD + h) * HDIM + d) * SEQ + (m0 & 1023) + sp8) = val;
      }
    }
  }
}

// ---------------------------------------------------------------------------
// K4: flash attention, St = K*Q^T formulation (P feeds PV straight from regs).
// Block = 512 thr (8 waves x 16 q-rows = 128-row q-tile) x head. Grid 8x64.
// ---------------------------------------------------------------------------
__global__ __launch_bounds__(512) void attn_kernel(
    const unsigned short* __restrict__ qb, const unsigned short* __restrict__ kb,
    const unsigned short* __restrict__ vtb, unsigned short* __restrict__ ao) {
  const int qt = blockIdx.x, head = blockIdx.y;
  const int b = head >> 3, h = head & 7;
  const int tid = threadIdx.x;
  const int wid = tid >> 6, lane = tid & 63;
  const int quad = lane >> 4, m16 = lane & 15;
  const int sw = m16 & 7;

  __shared__ alignas(16) unsigned short sK[128 * 64];   // swizzled, stride 64
  __shared__ alignas(16) unsigned short sV[64 * 128];   // Vt, swizzled, stride 128

  // Q fragments (pre-scaled by 1/64 upstream); B-operand layout == A layout
  const size_t qrow = (size_t)head * SEQ + qt * 128 + wid * 16 + m16;
  short8 aq0 = *(const short8*)(qb + qrow * HDIM + quad * 8);
  short8 aq1 = *(const short8*)(qb + qrow * HDIM + 32 + quad * 8);

  float mrun = -3.0e38f, lrun = 0.f;
  floatx4 o[4];
  for (int df = 0; df < 4; ++df) o[df] = 0.f;

  for (int kt = 0; kt < 8; ++kt) {
    // stage K tile (128x64) and Vt tile (64x128) via async DMA
    for (int i = 0; i < 2; ++i) {
      int c = i * 512 + tid;
      int r = c >> 3, kc = c & 7;
      load_lds16(kb + ((size_t)head * SEQ + kt * 128 + r) * HDIM + ((kc ^ (r & 7)) << 3),
                 &sK[c << 3]);
    }
    for (int i = 0; i < 2; ++i) {
      int c = i * 512 + tid;
      int d = c >> 4, kc = c & 15;
      load_lds16(vtb + ((size_t)head * HDIM + d) * SEQ + kt * 128 + ((kc ^ (d & 7)) << 3),
                 &sV[c << 3]);
    }
    __syncthreads();

    // St[s][q] = K*Q^T : A = K rows (m = s), B = Q (n = q)
    floatx4 st[8];
    for (int sf = 0; sf < 8; ++sf) {
      const int rb = (sf * 16 + m16) * 64;
      short8 k0 = *(const short8*)&sK[rb + ((quad ^ sw) << 3)];
      short8 k1 = *(const short8*)&sK[rb + (((4 + quad) ^ sw) << 3)];
      floatx4 s = 0.f;
      s = __builtin_amdgcn_mfma_f32_16x16x32_bf16(k0, aq0, s, 0, 0, 0);
      s = __builtin_amdgcn_mfma_f32_16x16x32_bf16(k1, aq1, s, 0, 0, 0);
      st[sf] = s;
    }

    // online softmax: lane holds 32 scores of q-col m16; reduce across quads
    float mx = -3.0e38f;
    for (int sf = 0; sf < 8; ++sf)
      for (int r = 0; r < 4; ++r) mx = fmaxf(mx, st[sf][r]);
    mx = fmaxf(mx, __shfl_xor(mx, 16));
    mx = fmaxf(mx, __shfl_xor(mx, 32));
    float mnew = fmaxf(mrun, mx);
    float alpha = __expf(mrun - mnew);
    float rs = 0.f;
    for (int sf = 0; sf < 8; ++sf)
      for (int r = 0; r < 4; ++r) {
        float p = __expf(st[sf][r] - mnew);
        st[sf][r] = p;
        rs += p;
      }
    rs += __shfl_xor(rs, 16);
    rs += __shfl_xor(rs, 32);
    mrun = mnew;
    lrun = lrun * alpha + rs;

    // redistribute alpha to O rows (row = quad*4+reg, alpha indexed by m16)
    const int asrc = (quad << 4) + (quad << 2);
    float a0 = __shfl(alpha, asrc + 0), a1 = __shfl(alpha, asrc + 1);
    float a2 = __shfl(alpha, asrc + 2), a3 = __shfl(alpha, asrc + 3);
    for (int df = 0; df < 4; ++df) {
      o[df][0] *= a0; o[df][1] *= a1; o[df][2] *= a2; o[df][3] *= a3;
    }

    // pack P: St C-layout == 16x16x16 A-operand layout (k = quad*4+reg)
    short4v pf[8];
    for (int sf = 0; sf < 8; ++sf)
      for (int r = 0; r < 4; ++r) pf[sf][r] = (short)f2bf(st[sf][r]);

    // O += P*V  (B-frags: Vt rows, b64 reads, swizzled)
    for (int kc = 0; kc < 8; ++kc) {
      int slot = ((((kc << 1) + (quad >> 1)) ^ sw) << 3) + ((quad & 1) << 2);
      for (int df = 0; df < 4; ++df) {
        short4v bv = *(const short4v*)&sV[(df * 16 + m16) * 128 + slot];
        o[df] = __builtin_amdgcn_mfma_f32_16x16x16bf16_1k(pf[kc], bv, o[df], 0, 0, 0);
      }
    }
    __syncthreads();
  }

  // normalize, write bf16 (b, seq, C)
  float linv = 1.0f / lrun;
  const int asrc = (quad << 4) + (quad << 2);
  float l0 = __shfl(linv, asrc + 0), l1 = __shfl(linv, asrc + 1);
  float l2 = __shfl(linv, asrc + 2), l3 = __shfl(linv, asrc + 3);
  int qg = qt * 128 + wid * 16 + quad * 4;
  for (int df = 0; df < 4; ++df) {
    int col = h * HDIM + df * 16 + m16;
    size_t base = (size_t)(b * SEQ + qg) * CH + col;
    ao[base + 0 * CH] = f2bf(o[df][0] * l0);
    ao[base + 1 * CH] = f2bf(o[df][1] * l1);
    ao[base + 2 * CH] = f2bf(o[df][2] * l2);
    ao[base + 3 * CH] = f2bf(o[df][3] * l3);
  }
}

// ---------------------------------------------------------------------------
extern "C" void kernel_launch(void* const* d_in, const int* in_sizes, int n_in,
                              void* d_out, int out_size, void* d_ws, size_t ws_size,
                              hipStream_t stream) {
  const float* x    = (const float*)d_in[0];
  const float* gsc  = (const float*)d_in[1];
  const float* gbs  = (const float*)d_in[2];
  const float* wqkv = (const float*)d_in[3];
  const float* bqkv = (const float*)d_in[4];
  const float* wout = (const float*)d_in[5];
  const float* bout = (const float*)d_in[6];
  float* out = (float*)d_out;

  char* ws = (char*)d_ws;
  unsigned short* xn    = (unsigned short*)(ws);                 // 8 MB (8192x512)
  unsigned short* wqkvt = (unsigned short*)(ws + 8388608);       // 1.5 MB (1536x512)
  unsigned short* woutt = (unsigned short*)(ws + 9961472);       // 0.5 MB (512x512)
  unsigned short* qb    = (unsigned short*)(ws + 10485760);      // 8 MB (64,1024,64)
  unsigned short* kb    = (unsigned short*)(ws + 18874368);      // 8 MB (64,1024,64)
  unsigned short* vtb   = (unsigned short*)(ws + 27262976);      // 8 MB (64,64,1024)
  unsigned short* ao    = (unsigned short*)(ws + 35651584);      // 8 MB (8192x512)

  transpose_bf16_kernel<<<dim3(48, 16), 256, 0, stream>>>(wqkv, wqkvt, 512, 1536);
  transpose_bf16_kernel<<<dim3(16, 16), 256, 0, stream>>>(wout, woutt, 512, 512);
  groupnorm_kernel<<<256, 256, 0, stream>>>(x, gsc, gbs, xn);
  gemm_bt_kernel<0><<<dim3(12, 64), 256, 0, stream>>>(
      xn, wqkvt, 512, 1536, bqkv, nullptr, nullptr, qb, kb, vtb);
  attn_kernel<<<dim3(8, 64), 512, 0, stream>>>(qb, kb, vtb, ao);
  gemm_bt_kernel<1><<<dim3(4, 64), 256, 0, stream>>>(
      ao, woutt, 512, 512, bout, x, out, nullptr, nullptr, nullptr);
}